// Round 2
// baseline (823.690 us; speedup 1.0000x reference)
//
#include <hip/hip_runtime.h>

#define R_TOTAL 12544
#define NTOK    784
#define CDIM    384
#define INNER   1152
#define NHEAD   8
#define HDIM    48
#define BATCH   16
#define SCALE   0.14433756729740643f   // 48^-0.5

typedef unsigned short u16;
typedef unsigned int   u32;

// workspace layout (BYTE offsets) — total 38.6 MB (round 1 proved >77MB unsafe: OOB ws writes
// corrupted the harness's pristine input copies; stay small)
#define YB_BYTES   28901376ull   // [12544,1152] bf16 qkv pre-BN
#define OB_BYTES    9633792ull   // [12544,384]  bf16 attention out
#define OB_OFF     28901376ull
#define ST_OFF     38535168ull   // fp32 stats: S1[2304] AB1[2304] S2[768] AB2[768]

__device__ __forceinline__ float b2f(u16 u) {
    union { float f; u32 i; } v; v.i = ((u32)u) << 16; return v.f;
}
__device__ __forceinline__ u16 f2b(float f) {
    union { float f; u32 i; } v; v.f = f;
    u32 r = v.i + 0x7FFFu + ((v.i >> 16) & 1u);   // RNE
    return (u16)(r >> 16);
}
__device__ __forceinline__ float hswish_f(float v) {
    return v * fminf(fmaxf(v + 3.f, 0.f), 6.f) * (1.f / 6.f);
}

__global__ __launch_bounds__(256) void zero_k(float* __restrict__ p, int n) {
    int i = blockIdx.x * 256 + threadIdx.x;
    if (i < n) p[i] = 0.f;
}

// ---------------------------------------------------------------- tiled GEMM
// A row-major [M,K] (fp32 or bf16, optional hardswish), Bt row-major [N,K] fp32, C = A*Bt^T
template<int ABF16, int HSW, int OBF16>
__global__ __launch_bounds__(256) void gemm_bt_k(
    const void* __restrict__ Ap, const float* __restrict__ Bt,
    void* __restrict__ Cp, int M, int Nout, int K)
{
    __shared__ float As[16][68];
    __shared__ float Bs[16][68];
    const int t  = threadIdx.x;
    const int tx = t & 15, ty = t >> 4;
    const int n0 = blockIdx.x * 64;
    const int m0 = blockIdx.y * 64;
    const int lr = t >> 2;            // 0..63
    const int lc = (t & 3) << 2;      // 0,4,8,12

    float acc[4][4];
    #pragma unroll
    for (int i = 0; i < 4; i++)
        #pragma unroll
        for (int j = 0; j < 4; j++) acc[i][j] = 0.f;

    for (int k0 = 0; k0 < K; k0 += 16) {
        __syncthreads();
        float a0, a1, a2, a3;
        if (ABF16) {
            const u16* A = (const u16*)Ap;
            ushort4 uv = *(const ushort4*)(A + (size_t)(m0 + lr) * K + k0 + lc);
            a0 = b2f(uv.x); a1 = b2f(uv.y); a2 = b2f(uv.z); a3 = b2f(uv.w);
        } else {
            const float* A = (const float*)Ap;
            float4 av = *(const float4*)(A + (size_t)(m0 + lr) * K + k0 + lc);
            a0 = av.x; a1 = av.y; a2 = av.z; a3 = av.w;
        }
        if (HSW) { a0 = hswish_f(a0); a1 = hswish_f(a1); a2 = hswish_f(a2); a3 = hswish_f(a3); }
        As[lc + 0][lr] = a0; As[lc + 1][lr] = a1;
        As[lc + 2][lr] = a2; As[lc + 3][lr] = a3;
        float4 bv = *(const float4*)(Bt + (size_t)(n0 + lr) * K + k0 + lc);
        Bs[lc + 0][lr] = bv.x; Bs[lc + 1][lr] = bv.y;
        Bs[lc + 2][lr] = bv.z; Bs[lc + 3][lr] = bv.w;
        __syncthreads();
        #pragma unroll
        for (int kk = 0; kk < 16; kk++) {
            float4 a4 = *(const float4*)&As[kk][ty << 2];
            float4 b4 = *(const float4*)&Bs[kk][tx << 2];
            float aa[4] = {a4.x, a4.y, a4.z, a4.w};
            float bb[4] = {b4.x, b4.y, b4.z, b4.w};
            #pragma unroll
            for (int i = 0; i < 4; i++)
                #pragma unroll
                for (int j = 0; j < 4; j++) acc[i][j] += aa[i] * bb[j];
        }
    }
    #pragma unroll
    for (int i = 0; i < 4; i++) {
        size_t off = (size_t)(m0 + ty * 4 + i) * Nout + n0 + (tx << 2);
        if (OBF16) {
            u16* C = (u16*)Cp;
            ushort4 o4 = make_ushort4(f2b(acc[i][0]), f2b(acc[i][1]), f2b(acc[i][2]), f2b(acc[i][3]));
            *(ushort4*)(C + off) = o4;
        } else {
            float* C = (float*)Cp;
            *(float4*)(C + off) = make_float4(acc[i][0], acc[i][1], acc[i][2], acc[i][3]);
        }
    }
}

// ---------------------------------------------------------------- column stats (sum, sumsq)
template<int BF16>
__global__ __launch_bounds__(128) void col_stats_k(
    const void* __restrict__ Zp, float* __restrict__ sums, int Ncols)
{
    const int col = blockIdx.x * 128 + threadIdx.x;
    const int r0  = blockIdx.y * 256;
    float s = 0.f, s2 = 0.f;
    if (BF16) {
        const u16* Z = (const u16*)Zp;
        for (int r = r0; r < r0 + 256; r++) {
            float v = b2f(Z[(size_t)r * Ncols + col]);
            s += v; s2 += v * v;
        }
    } else {
        const float* Z = (const float*)Zp;
        for (int r = r0; r < r0 + 256; r++) {
            float v = Z[(size_t)r * Ncols + col];
            s += v; s2 += v * v;
        }
    }
    atomicAdd(&sums[col], s);
    atomicAdd(&sums[Ncols + col], s2);
}

__global__ __launch_bounds__(256) void finalize_bn_k(
    const float* __restrict__ sums, const float* __restrict__ g,
    const float* __restrict__ bvec, float* __restrict__ ab, int Ncols, float invM)
{
    int c = blockIdx.x * 256 + threadIdx.x;
    if (c >= Ncols) return;
    float mean = sums[c] * invM;
    float var  = sums[Ncols + c] * invM - mean * mean;
    float a    = g[c] * rsqrtf(var + 1e-5f);
    ab[c] = a;
    ab[Ncols + c] = bvec[c] - mean * a;
}

__global__ __launch_bounds__(256) void bn_apply_k(
    float* __restrict__ Z, const float* __restrict__ ab, int Ncols, int total4)
{
    for (int i4 = blockIdx.x * 256 + threadIdx.x; i4 < total4; i4 += gridDim.x * 256) {
        int col = (i4 * 4) % Ncols;
        float4 z  = *(float4*)(Z + (size_t)i4 * 4);
        float4 a4 = *(const float4*)(ab + col);
        float4 b4 = *(const float4*)(ab + Ncols + col);
        z.x = a4.x * z.x + b4.x; z.y = a4.y * z.y + b4.y;
        z.z = a4.z * z.z + b4.z; z.w = a4.w * z.w + b4.w;
        *(float4*)(Z + (size_t)i4 * 4) = z;
    }
}

// ---------------------------------------------------------------- attention (flash-style, fp32 math, bf16 storage)
// loads a 64-row x 48-col tile of bf16 Y (applying BN a*y+bb in fp32), stores TRANSPOSED dst[d][row]
__device__ __forceinline__ void load_tileT(
    float (*dst)[68], const u16* __restrict__ Y,
    const float* __restrict__ av, const float* __restrict__ bbv,
    int grow0, int nvalid, int colbase, int t)
{
    #pragma unroll
    for (int it = 0; it < 3; it++) {
        int f  = t + it * 256;            // 0..767
        int r  = f / 12;                  // tile row 0..63
        int c4 = (f % 12) << 2;           // 0..44 step 4
        float x0 = 0.f, x1 = 0.f, x2 = 0.f, x3 = 0.f;
        if (r < nvalid) {
            ushort4 uv = *(const ushort4*)(Y + (size_t)(grow0 + r) * INNER + colbase + c4);
            float4 a4 = *(const float4*)(av + colbase + c4);
            float4 b4 = *(const float4*)(bbv + colbase + c4);
            x0 = a4.x * b2f(uv.x) + b4.x; x1 = a4.y * b2f(uv.y) + b4.y;
            x2 = a4.z * b2f(uv.z) + b4.z; x3 = a4.w * b2f(uv.w) + b4.w;
        }
        dst[c4 + 0][r] = x0; dst[c4 + 1][r] = x1;
        dst[c4 + 2][r] = x2; dst[c4 + 3][r] = x3;
    }
}

__global__ __launch_bounds__(256) void attn_k(
    const u16* __restrict__ Y, const float* __restrict__ ab1,
    const float* __restrict__ biases, const int* __restrict__ idxs,
    u16* __restrict__ O)
{
    __shared__ float qs[48][68];
    __shared__ float kts[48][68];
    __shared__ float vts[48][68];
    __shared__ float ps[64][68];
    __shared__ float hb[NTOK];

    const int t  = threadIdx.x;
    const int tx = t & 15, ty = t >> 4;
    const int qt = blockIdx.x, h = blockIdx.y, b = blockIdx.z;
    const int n0 = qt * 64;
    const float* av  = ab1;
    const float* bbv = ab1 + INNER;

    // per-head bias row into LDS (784 floats)
    if (t < 196) {
        float4 v = *(const float4*)(biases + (size_t)h * NTOK + (t << 2));
        *(float4*)&hb[t << 2] = v;
    }
    load_tileT(qs, Y, av, bbv, b * NTOK + n0, NTOK - n0, h * HDIM, t);

    float oa[4][3];
    float mrun[4], lrun[4];
    #pragma unroll
    for (int i = 0; i < 4; i++) {
        mrun[i] = -1e30f; lrun[i] = 0.f;
        oa[i][0] = 0.f; oa[i][1] = 0.f; oa[i][2] = 0.f;
    }

    for (int mt = 0; mt < 13; mt++) {
        const int m0 = mt * 64;
        __syncthreads();  // prev PV done; also fences qs/hb at mt=0
        load_tileT(kts, Y, av, bbv, b * NTOK + m0, NTOK - m0, CDIM + h * HDIM, t);
        load_tileT(vts, Y, av, bbv, b * NTOK + m0, NTOK - m0, 2 * CDIM + h * HDIM, t);
        __syncthreads();

        // ---- QK^T: rows n0+ty*4+i, cols m0+tx*4+j
        float s[4][4];
        #pragma unroll
        for (int i = 0; i < 4; i++)
            #pragma unroll
            for (int j = 0; j < 4; j++) s[i][j] = 0.f;
        #pragma unroll 8
        for (int k = 0; k < 48; k++) {
            float4 a4 = *(const float4*)&qs[k][ty << 2];
            float4 b4 = *(const float4*)&kts[k][tx << 2];
            float aa[4] = {a4.x, a4.y, a4.z, a4.w};
            float bb[4] = {b4.x, b4.y, b4.z, b4.w};
            #pragma unroll
            for (int i = 0; i < 4; i++)
                #pragma unroll
                for (int j = 0; j < 4; j++) s[i][j] += aa[i] * bb[j];
        }
        // ---- scale + rel-pos bias (LDS gather via idxs) + col mask
        // NTOK%4==0 -> each int4 at mj0 is either fully valid (mj0+3<784) or fully masked (mj0>=784)
        const int mj0 = m0 + (tx << 2);
        const bool mvalid = (mj0 < NTOK);
        #pragma unroll
        for (int i = 0; i < 4; i++) {
            int n  = n0 + ty * 4 + i;
            int nc = n < NTOK ? n : NTOK - 1;
            if (mvalid) {
                int4 iv = *(const int4*)(idxs + (size_t)nc * NTOK + mj0);
                s[i][0] = s[i][0] * SCALE + hb[iv.x];
                s[i][1] = s[i][1] * SCALE + hb[iv.y];
                s[i][2] = s[i][2] * SCALE + hb[iv.z];
                s[i][3] = s[i][3] * SCALE + hb[iv.w];
            } else {
                s[i][0] = -1e30f; s[i][1] = -1e30f; s[i][2] = -1e30f; s[i][3] = -1e30f;
            }
        }
        // ---- online softmax (16 lanes sharing ty, same wave)
        #pragma unroll
        for (int i = 0; i < 4; i++) {
            float mx = fmaxf(fmaxf(s[i][0], s[i][1]), fmaxf(s[i][2], s[i][3]));
            mx = fmaxf(mx, __shfl_xor(mx, 1));
            mx = fmaxf(mx, __shfl_xor(mx, 2));
            mx = fmaxf(mx, __shfl_xor(mx, 4));
            mx = fmaxf(mx, __shfl_xor(mx, 8));
            float mnew  = fmaxf(mrun[i], mx);
            float alpha = __expf(mrun[i] - mnew);
            float p0 = __expf(s[i][0] - mnew);
            float p1 = __expf(s[i][1] - mnew);
            float p2 = __expf(s[i][2] - mnew);
            float p3 = __expf(s[i][3] - mnew);
            float psum = p0 + p1 + p2 + p3;
            psum += __shfl_xor(psum, 1);
            psum += __shfl_xor(psum, 2);
            psum += __shfl_xor(psum, 4);
            psum += __shfl_xor(psum, 8);
            lrun[i] = lrun[i] * alpha + psum;
            mrun[i] = mnew;
            oa[i][0] *= alpha; oa[i][1] *= alpha; oa[i][2] *= alpha;
            *(float4*)&ps[(ty << 2) + i][tx << 2] = make_float4(p0, p1, p2, p3);
        }
        __syncthreads();
        // ---- PV
        #pragma unroll 4
        for (int mq = 0; mq < 16; mq++) {
            float pr[4][4], vr[3][4];
            #pragma unroll
            for (int i = 0; i < 4; i++) {
                float4 p4 = *(const float4*)&ps[(ty << 2) + i][mq << 2];
                pr[i][0] = p4.x; pr[i][1] = p4.y; pr[i][2] = p4.z; pr[i][3] = p4.w;
            }
            #pragma unroll
            for (int j = 0; j < 3; j++) {
                float4 v4 = *(const float4*)&vts[tx * 3 + j][mq << 2];
                vr[j][0] = v4.x; vr[j][1] = v4.y; vr[j][2] = v4.z; vr[j][3] = v4.w;
            }
            #pragma unroll
            for (int i = 0; i < 4; i++)
                #pragma unroll
                for (int j = 0; j < 3; j++)
                    #pragma unroll
                    for (int mm = 0; mm < 4; mm++)
                        oa[i][j] += pr[i][mm] * vr[j][mm];
        }
    }
    // ---- epilogue -> bf16 O[b*784+n][h*48 + tx*3 + j]
    #pragma unroll
    for (int i = 0; i < 4; i++) {
        int n = n0 + ty * 4 + i;
        if (n < NTOK) {
            float rl = 1.f / lrun[i];
            size_t base = ((size_t)b * NTOK + n) * CDIM + h * HDIM + tx * 3;
            O[base + 0] = f2b(oa[i][0] * rl);
            O[base + 1] = f2b(oa[i][1] * rl);
            O[base + 2] = f2b(oa[i][2] * rl);
        }
    }
}

// ---------------------------------------------------------------- launch
extern "C" void kernel_launch(void* const* d_in, const int* in_sizes, int n_in,
                              void* d_out, int out_size, void* d_ws, size_t ws_size,
                              hipStream_t stream)
{
    const float* x     = (const float*)d_in[0];
    const float* Wqkv  = (const float*)d_in[1];
    const float* g1    = (const float*)d_in[2];
    const float* b1    = (const float*)d_in[3];
    const float* Wproj = (const float*)d_in[4];
    const float* g2    = (const float*)d_in[5];
    const float* b2    = (const float*)d_in[6];
    const float* bias  = (const float*)d_in[7];
    const int*   idxs  = (const int*)d_in[8];
    float* out = (float*)d_out;
    char*  wsb = (char*)d_ws;

    u16*   Yb  = (u16*)wsb;                    // 28.9 MB
    u16*   Ob  = (u16*)(wsb + OB_OFF);         // 9.6 MB
    float* S1  = (float*)(wsb + ST_OFF);       // 2304
    float* AB1 = S1 + 2304;                    // 2304
    float* S2  = AB1 + 2304;                   // 768
    float* AB2 = S2 + 768;                     // 768

    zero_k<<<24, 256, 0, stream>>>(S1, 6144);

    // GEMM1: Ybf16 = x @ Wqkv^T   [12544,1152]
    gemm_bt_k<0, 0, 1><<<dim3(INNER / 64, R_TOTAL / 64), 256, 0, stream>>>(
        x, Wqkv, Yb, R_TOTAL, INNER, CDIM);

    // BN1 stats -> a, bb
    col_stats_k<1><<<dim3(INNER / 128, R_TOTAL / 256), 128, 0, stream>>>(Yb, S1, INNER);
    finalize_bn_k<<<(INNER + 255) / 256, 256, 0, stream>>>(S1, g1, b1, AB1, INNER, 1.f / R_TOTAL);

    // attention (BN applied on the fly, bias gathered from LDS)
    attn_k<<<dim3(13, NHEAD, BATCH), 256, 0, stream>>>(Yb, AB1, bias, idxs, Ob);

    // GEMM2: out = hardswish(O) @ Wproj^T   [12544,384]
    gemm_bt_k<1, 1, 0><<<dim3(CDIM / 64, R_TOTAL / 64), 256, 0, stream>>>(
        Ob, Wproj, out, R_TOTAL, CDIM, CDIM);

    // BN2 stats -> normalize out in place
    col_stats_k<0><<<dim3(CDIM / 128, R_TOTAL / 256), 128, 0, stream>>>(out, S2, CDIM);
    finalize_bn_k<<<(CDIM + 255) / 256, 256, 0, stream>>>(S2, g2, b2, AB2, CDIM, 1.f / R_TOTAL);
    bn_apply_k<<<1024, 256, 0, stream>>>(out, AB2, CDIM, (R_TOTAL * CDIM) / 4);
}

// Round 3
// 336.984 us; speedup vs baseline: 2.4443x; 2.4443x over previous
//
#include <hip/hip_runtime.h>

#define R_TOTAL 12544
#define NTOK    784
#define CDIM    384
#define INNER   1152
#define NHEAD   8
#define HDIM    48
#define BATCH   16
#define SCALE   0.14433756729740643f   // 48^-0.5

typedef unsigned short u16;
typedef unsigned int   u32;
typedef __attribute__((ext_vector_type(8))) short short8;   // 8 bf16, 4 VGPRs (guide §3)
typedef __attribute__((ext_vector_type(4))) float floatx4;  // MFMA C/D

union V8 { uint4 u; short8 s; };

// workspace layout (BYTE offsets) — total 38.56 MB, byte-identical to round-2-proven layout.
// Round 1 proved larger layouts corrupt the harness's pristine input copies.
#define OB_OFF     28901376ull   // Yb bf16 [12544,1152] at 0; Ob bf16 [12544,384] here
#define ST_OFF     38535168ull   // fp32 stats: S1[2304] AB1[2304] S2[768] AB2[768]

__device__ __forceinline__ float b2f(u16 u) {
    union { float f; u32 i; } v; v.i = ((u32)u) << 16; return v.f;
}
__device__ __forceinline__ u16 f2b(float f) {
    union { float f; u32 i; } v; v.f = f;
    u32 r = v.i + 0x7FFFu + ((v.i >> 16) & 1u);   // RNE
    return (u16)(r >> 16);
}
__device__ __forceinline__ u32 pk2(float lo, float hi) {
    return (u32)f2b(lo) | ((u32)f2b(hi) << 16);
}
__device__ __forceinline__ float hswish_f(float v) {
    return v * fminf(fmaxf(v + 3.f, 0.f), 6.f) * (1.f / 6.f);
}

// load 8 bf16 from global, apply BN (a*y+b) in fp32, repack to bf16 frag
__device__ __forceinline__ short8 bn8(const u16* __restrict__ src,
                                      const float* __restrict__ a,
                                      const float* __restrict__ bb)
{
    uint4 u = *(const uint4*)src;
    float4 A0 = *(const float4*)a,  A1 = *(const float4*)(a + 4);
    float4 B0 = *(const float4*)bb, B1 = *(const float4*)(bb + 4);
    V8 r;
    r.u.x = pk2(fmaf(b2f((u16)(u.x & 0xffff)), A0.x, B0.x), fmaf(b2f((u16)(u.x >> 16)), A0.y, B0.y));
    r.u.y = pk2(fmaf(b2f((u16)(u.y & 0xffff)), A0.z, B0.z), fmaf(b2f((u16)(u.y >> 16)), A0.w, B0.w));
    r.u.z = pk2(fmaf(b2f((u16)(u.z & 0xffff)), A1.x, B1.x), fmaf(b2f((u16)(u.z >> 16)), A1.y, B1.y));
    r.u.w = pk2(fmaf(b2f((u16)(u.w & 0xffff)), A1.z, B1.z), fmaf(b2f((u16)(u.w >> 16)), A1.w, B1.w));
    return r.s;
}

__global__ __launch_bounds__(256) void zero_k(float* __restrict__ p, int n) {
    int i = blockIdx.x * 256 + threadIdx.x;
    if (i < n) p[i] = 0.f;
}

// ---------------------------------------------------------------- MFMA GEMM
// A row-major [M,K] (fp32 or bf16, optional hardswish), Bt row-major [N,K] fp32,
// C = A*Bt^T, out bf16 or fp32. 128x128 tile, BK=32, 4 waves of 64x64.
template<int ABF16, int HSW, int OBF16>
__global__ __launch_bounds__(256) void gemm_mfma_k(
    const void* __restrict__ Ap, const float* __restrict__ Bfp,
    void* __restrict__ Cp, int M, int Nout, int K)
{
    __shared__ u16 As[128 * 40];   // row stride 40 shorts (pad 8) -> 2-way banks
    __shared__ u16 Bs[128 * 40];
    const int t = threadIdx.x;
    const int lane = t & 63, wv = t >> 6;
    const int l15 = lane & 15, quad = lane >> 4;
    const int wm = (wv & 1) * 64, wn = (wv >> 1) * 64;
    const int m0 = blockIdx.y * 128, n0 = blockIdx.x * 128;
    const floatx4 zf = {0.f, 0.f, 0.f, 0.f};

    floatx4 acc[4][4];
    #pragma unroll
    for (int i = 0; i < 4; i++)
        #pragma unroll
        for (int j = 0; j < 4; j++) acc[i][j] = zf;

    for (int k0 = 0; k0 < K; k0 += 32) {
        __syncthreads();
        #pragma unroll
        for (int it = 0; it < 2; it++) {
            const int flat = t + it * 256;           // 0..511
            const int rr = flat >> 2, ss = (flat & 3) * 8;
            uint4 aw;
            if (ABF16) {
                uint4 u = *(const uint4*)((const u16*)Ap + (size_t)(m0 + rr) * K + k0 + ss);
                if (HSW) {
                    aw.x = pk2(hswish_f(b2f((u16)(u.x & 0xffff))), hswish_f(b2f((u16)(u.x >> 16))));
                    aw.y = pk2(hswish_f(b2f((u16)(u.y & 0xffff))), hswish_f(b2f((u16)(u.y >> 16))));
                    aw.z = pk2(hswish_f(b2f((u16)(u.z & 0xffff))), hswish_f(b2f((u16)(u.z >> 16))));
                    aw.w = pk2(hswish_f(b2f((u16)(u.w & 0xffff))), hswish_f(b2f((u16)(u.w >> 16))));
                } else {
                    aw = u;
                }
            } else {
                const float* p = (const float*)Ap + (size_t)(m0 + rr) * K + k0 + ss;
                float4 f0 = *(const float4*)p, f1 = *(const float4*)(p + 4);
                aw.x = pk2(f0.x, f0.y); aw.y = pk2(f0.z, f0.w);
                aw.z = pk2(f1.x, f1.y); aw.w = pk2(f1.z, f1.w);
            }
            *(uint4*)&As[rr * 40 + ss] = aw;
            const float* q = Bfp + (size_t)(n0 + rr) * K + k0 + ss;
            float4 g0 = *(const float4*)q, g1 = *(const float4*)(q + 4);
            uint4 bw;
            bw.x = pk2(g0.x, g0.y); bw.y = pk2(g0.z, g0.w);
            bw.z = pk2(g1.x, g1.y); bw.w = pk2(g1.z, g1.w);
            *(uint4*)&Bs[rr * 40 + ss] = bw;
        }
        __syncthreads();
        short8 af[4], bfr[4];
        #pragma unroll
        for (int mi = 0; mi < 4; mi++)
            af[mi] = *(const short8*)&As[(wm + mi * 16 + l15) * 40 + quad * 8];
        #pragma unroll
        for (int ni = 0; ni < 4; ni++)
            bfr[ni] = *(const short8*)&Bs[(wn + ni * 16 + l15) * 40 + quad * 8];
        #pragma unroll
        for (int mi = 0; mi < 4; mi++)
            #pragma unroll
            for (int ni = 0; ni < 4; ni++)
                acc[mi][ni] = __builtin_amdgcn_mfma_f32_16x16x32_bf16(af[mi], bfr[ni], acc[mi][ni], 0, 0, 0);
    }
    #pragma unroll
    for (int mi = 0; mi < 4; mi++) {
        const int mbase = m0 + wm + mi * 16 + quad * 4;
        #pragma unroll
        for (int ni = 0; ni < 4; ni++) {
            const int n = n0 + wn + ni * 16 + l15;
            #pragma unroll
            for (int reg = 0; reg < 4; reg++) {
                size_t off = (size_t)(mbase + reg) * Nout + n;
                float v = acc[mi][ni][reg];
                if (OBF16) ((u16*)Cp)[off] = f2b(v);
                else       ((float*)Cp)[off] = v;
            }
        }
    }
}

// ---------------------------------------------------------------- column stats (sum, sumsq)
template<int BF16>
__global__ __launch_bounds__(128) void col_stats_k(
    const void* __restrict__ Zp, float* __restrict__ sums, int Ncols)
{
    const int col = blockIdx.x * 128 + threadIdx.x;
    const int r0  = blockIdx.y * 256;
    float s = 0.f, s2 = 0.f;
    if (BF16) {
        const u16* Z = (const u16*)Zp;
        for (int r = r0; r < r0 + 256; r++) {
            float v = b2f(Z[(size_t)r * Ncols + col]);
            s += v; s2 += v * v;
        }
    } else {
        const float* Z = (const float*)Zp;
        for (int r = r0; r < r0 + 256; r++) {
            float v = Z[(size_t)r * Ncols + col];
            s += v; s2 += v * v;
        }
    }
    atomicAdd(&sums[col], s);
    atomicAdd(&sums[Ncols + col], s2);
}

__global__ __launch_bounds__(256) void finalize_bn_k(
    const float* __restrict__ sums, const float* __restrict__ g,
    const float* __restrict__ bvec, float* __restrict__ ab, int Ncols, float invM)
{
    int c = blockIdx.x * 256 + threadIdx.x;
    if (c >= Ncols) return;
    float mean = sums[c] * invM;
    float var  = sums[Ncols + c] * invM - mean * mean;
    float a    = g[c] * rsqrtf(var + 1e-5f);
    ab[c] = a;
    ab[Ncols + c] = bvec[c] - mean * a;
}

__global__ __launch_bounds__(256) void bn_apply_k(
    float* __restrict__ Z, const float* __restrict__ ab, int Ncols, int total4)
{
    for (int i4 = blockIdx.x * 256 + threadIdx.x; i4 < total4; i4 += gridDim.x * 256) {
        int col = (i4 * 4) % Ncols;
        float4 z  = *(float4*)(Z + (size_t)i4 * 4);
        float4 a4 = *(const float4*)(ab + col);
        float4 b4 = *(const float4*)(ab + Ncols + col);
        z.x = a4.x * z.x + b4.x; z.y = a4.y * z.y + b4.y;
        z.z = a4.z * z.z + b4.z; z.w = a4.w * z.w + b4.w;
        *(float4*)(Z + (size_t)i4 * 4) = z;
    }
}

// ---------------------------------------------------------------- MFMA flash attention
// 4 waves/block; wave w owns q-rows n0+w*16..+15; k-tiles of 64.
__global__ __launch_bounds__(256) void attn_mfma_k(
    const u16* __restrict__ Y, const float* __restrict__ ab1,
    const float* __restrict__ biases, const int* __restrict__ idxs,
    u16* __restrict__ O)
{
    __shared__ u16 kt[64 * 72];        // [key][hd padded to 64, stride 72]
    __shared__ u16 vt[48 * 72];        // [hd][key, stride 72] (transposed)
    __shared__ u16 psm[4][16 * 72];    // per-wave P [q][key, stride 72]
    __shared__ float hb[NTOK];

    const int t = threadIdx.x;
    const int lane = t & 63, wv = t >> 6;
    const int l15 = lane & 15, quad = lane >> 4;
    const int qt = blockIdx.x, h = blockIdx.y, b = blockIdx.z;
    const int n0 = qt * 64;
    const int bN = b * NTOK;
    const int colQ = h * HDIM, colK = CDIM + h * HDIM, colV = 2 * CDIM + h * HDIM;
    const float* av  = ab1;
    const float* bbv = ab1 + INNER;
    const floatx4 zf = {0.f, 0.f, 0.f, 0.f};

    if (t < 196) *(float4*)&hb[t << 2] = *(const float4*)(biases + (size_t)h * NTOK + (t << 2));
    if (t < 128) {   // zero the hd 48..63 pad of kt (QK chunk1 reads zeros there)
        uint4 z = make_uint4(0u, 0u, 0u, 0u);
        *(uint4*)&kt[(t >> 1) * 72 + 48 + (t & 1) * 8] = z;
    }

    // Q fragments in registers (A-layout: m=l15, k=quad*8+j); chunk1 zero-padded past hd=48
    short8 qf0, qf1;
    {
        V8 a0, a1;
        a0.u = make_uint4(0u, 0u, 0u, 0u); a1.u = a0.u;
        int q = n0 + wv * 16 + l15;
        if (q < NTOK) {
            const u16* src = Y + (size_t)(bN + q) * INNER + colQ;
            a0.s = bn8(src + quad * 8, av + colQ + quad * 8, bbv + colQ + quad * 8);
            if (quad < 2)
                a1.s = bn8(src + 32 + quad * 8, av + colQ + 32 + quad * 8, bbv + colQ + 32 + quad * 8);
        }
        qf0 = a0.s; qf1 = a1.s;
    }

    float mrun[4], lrun[4];
    floatx4 oacc[3];
    #pragma unroll
    for (int i = 0; i < 4; i++) { mrun[i] = -1e30f; lrun[i] = 0.f; }
    #pragma unroll
    for (int i = 0; i < 3; i++) oacc[i] = zf;

    for (int mt = 0; mt < 13; mt++) {
        const int m0k = mt * 64;
        __syncthreads();   // prev iter consumed kt/vt; also fences hb/pad at mt=0
        #pragma unroll
        for (int it = 0; it < 2; it++) {
            int flat = t + (it << 8);
            if (flat < 384) {                       // 64 keys x 6 segs of 8 hd
                int r = flat / 6, s8 = (flat % 6) * 8;
                int key = m0k + r;
                V8 kv, vv;
                kv.u = make_uint4(0u, 0u, 0u, 0u); vv.u = kv.u;
                if (key < NTOK) {
                    const u16* base = Y + (size_t)(bN + key) * INNER;
                    kv.s = bn8(base + colK + s8, av + colK + s8, bbv + colK + s8);
                    vv.s = bn8(base + colV + s8, av + colV + s8, bbv + colV + s8);
                }
                *(uint4*)&kt[r * 72 + s8] = kv.u;
                #pragma unroll
                for (int j = 0; j < 8; j++) vt[(s8 + j) * 72 + r] = (u16)vv.s[j];
            }
        }
        __syncthreads();

        // ---- QK^T: D[q=quad*4+reg][key=sub*16+l15]
        floatx4 sf[4];
        #pragma unroll
        for (int sub = 0; sub < 4; sub++) {
            const u16* kr = &kt[(sub * 16 + l15) * 72 + quad * 8];
            short8 kb0 = *(const short8*)kr;
            short8 kb1 = *(const short8*)(kr + 32);
            floatx4 c = zf;
            c = __builtin_amdgcn_mfma_f32_16x16x32_bf16(qf0, kb0, c, 0, 0, 0);
            c = __builtin_amdgcn_mfma_f32_16x16x32_bf16(qf1, kb1, c, 0, 0, 0);
            sf[sub] = c;
        }

        // ---- scale + gathered bias + mask + online softmax + P->LDS (bf16)
        #pragma unroll
        for (int reg = 0; reg < 4; reg++) {
            int q = n0 + wv * 16 + quad * 4 + reg;
            int qc = q < NTOK ? q : NTOK - 1;
            const int* idxrow = idxs + (size_t)qc * NTOK;
            float sv[4];
            #pragma unroll
            for (int sub = 0; sub < 4; sub++) {
                int key = m0k + sub * 16 + l15;
                float x = sf[sub][reg] * SCALE;
                sv[sub] = (key < NTOK) ? x + hb[idxrow[key]] : -1e30f;
            }
            float mx = fmaxf(fmaxf(sv[0], sv[1]), fmaxf(sv[2], sv[3]));
            mx = fmaxf(mx, __shfl_xor(mx, 1));
            mx = fmaxf(mx, __shfl_xor(mx, 2));
            mx = fmaxf(mx, __shfl_xor(mx, 4));
            mx = fmaxf(mx, __shfl_xor(mx, 8));
            float mnew = fmaxf(mrun[reg], mx);
            float al = __expf(mrun[reg] - mnew);
            float psum = 0.f;
            u16* prow = &psm[wv][(quad * 4 + reg) * 72 + l15];
            #pragma unroll
            for (int sub = 0; sub < 4; sub++) {
                float p = __expf(sv[sub] - mnew);
                psum += p;
                prow[sub * 16] = f2b(p);
            }
            psum += __shfl_xor(psum, 1);
            psum += __shfl_xor(psum, 2);
            psum += __shfl_xor(psum, 4);
            psum += __shfl_xor(psum, 8);
            lrun[reg] = lrun[reg] * al + psum;
            mrun[reg] = mnew;
            oacc[0][reg] *= al; oacc[1][reg] *= al; oacc[2][reg] *= al;
        }

        // ---- PV: A=P (own wave's LDS tile, in-order per-wave DS), B=V^T
        #pragma unroll
        for (int kc = 0; kc < 2; kc++) {
            short8 pa = *(const short8*)&psm[wv][l15 * 72 + kc * 32 + quad * 8];
            #pragma unroll
            for (int ns = 0; ns < 3; ns++) {
                short8 vb = *(const short8*)&vt[(ns * 16 + l15) * 72 + kc * 32 + quad * 8];
                oacc[ns] = __builtin_amdgcn_mfma_f32_16x16x32_bf16(pa, vb, oacc[ns], 0, 0, 0);
            }
        }
    }

    // ---- epilogue: O[q][h*48 + ns*16 + l15] = oacc/l
    #pragma unroll
    for (int reg = 0; reg < 4; reg++) {
        int q = n0 + wv * 16 + quad * 4 + reg;
        if (q < NTOK) {
            float rl = 1.f / lrun[reg];
            u16* dst = O + (size_t)(bN + q) * CDIM + colQ;
            dst[l15]      = f2b(oacc[0][reg] * rl);
            dst[16 + l15] = f2b(oacc[1][reg] * rl);
            dst[32 + l15] = f2b(oacc[2][reg] * rl);
        }
    }
}

// ---------------------------------------------------------------- launch
extern "C" void kernel_launch(void* const* d_in, const int* in_sizes, int n_in,
                              void* d_out, int out_size, void* d_ws, size_t ws_size,
                              hipStream_t stream)
{
    const float* x     = (const float*)d_in[0];
    const float* Wqkv  = (const float*)d_in[1];
    const float* g1    = (const float*)d_in[2];
    const float* b1    = (const float*)d_in[3];
    const float* Wproj = (const float*)d_in[4];
    const float* g2    = (const float*)d_in[5];
    const float* b2    = (const float*)d_in[6];
    const float* bias  = (const float*)d_in[7];
    const int*   idxs  = (const int*)d_in[8];
    float* out = (float*)d_out;
    char*  wsb = (char*)d_ws;

    u16*   Yb  = (u16*)wsb;                    // 28.9 MB
    u16*   Ob  = (u16*)(wsb + OB_OFF);         // 9.6 MB
    float* S1  = (float*)(wsb + ST_OFF);       // 2304
    float* AB1 = S1 + 2304;                    // 2304
    float* S2  = AB1 + 2304;                   // 768
    float* AB2 = S2 + 768;                     // 768

    zero_k<<<24, 256, 0, stream>>>(S1, 6144);

    // GEMM1 (MFMA): Ybf16 = x @ Wqkv^T   [12544,1152]
    gemm_mfma_k<0, 0, 1><<<dim3(INNER / 128, R_TOTAL / 128), 256, 0, stream>>>(
        x, Wqkv, Yb, R_TOTAL, INNER, CDIM);

    // BN1 stats -> a, bb
    col_stats_k<1><<<dim3(INNER / 128, R_TOTAL / 256), 128, 0, stream>>>(Yb, S1, INNER);
    finalize_bn_k<<<(INNER + 255) / 256, 256, 0, stream>>>(S1, g1, b1, AB1, INNER, 1.f / R_TOTAL);

    // attention (MFMA, BN on the fly, bias gathered from LDS)
    attn_mfma_k<<<dim3(13, NHEAD, BATCH), 256, 0, stream>>>(Yb, AB1, bias, idxs, Ob);

    // GEMM2 (MFMA): out = hardswish(O) @ Wproj^T   [12544,384]
    gemm_mfma_k<1, 1, 0><<<dim3(CDIM / 128, R_TOTAL / 128), 256, 0, stream>>>(
        Ob, Wproj, out, R_TOTAL, CDIM, CDIM);

    // BN2 stats -> normalize out in place
    col_stats_k<0><<<dim3(CDIM / 128, R_TOTAL / 256), 128, 0, stream>>>(out, S2, CDIM);
    finalize_bn_k<<<(CDIM + 255) / 256, 256, 0, stream>>>(S2, g2, b2, AB2, CDIM, 1.f / R_TOTAL);
    bn_apply_k<<<1024, 256, 0, stream>>>(out, AB2, CDIM, (R_TOTAL * CDIM) / 4);
}